// Round 2
// baseline (769.448 us; speedup 1.0000x reference)
//
#include <hip/hip_runtime.h>

#define NEG_SLOPE 0.2f

__device__ __forceinline__ float wave_max64(float v) {
  for (int off = 32; off; off >>= 1) v = fmaxf(v, __shfl_xor(v, off));
  return v;
}
__device__ __forceinline__ float wave_sum64(float v) {
  for (int off = 32; off; off >>= 1) v += __shfl_xor(v, off);
  return v;
}

// ---------------- CSR build ----------------

__global__ void hist_k(const int* __restrict__ ei, int E, int E2, int* __restrict__ deg) {
  int i = blockIdx.x * 256 + threadIdx.x;
  if (i >= E2) return;
  int d = (i < E) ? ei[E + i] : (i - E);   // dst row of edge_index, or self-loop
  atomicAdd(&deg[d], 1);
}

// chunk = 1024 elements per block (256 threads x 4)
__global__ void scan1_k(const int* __restrict__ deg, int* __restrict__ excl,
                        int* __restrict__ bsum, int N) {
  __shared__ int sm[256];
  int t = threadIdx.x;
  int base = blockIdx.x * 1024 + t * 4;
  int v0 = (base + 0 < N) ? deg[base + 0] : 0;
  int v1 = (base + 1 < N) ? deg[base + 1] : 0;
  int v2 = (base + 2 < N) ? deg[base + 2] : 0;
  int v3 = (base + 3 < N) ? deg[base + 3] : 0;
  int tsum = v0 + v1 + v2 + v3;
  sm[t] = tsum;
  __syncthreads();
  for (int off = 1; off < 256; off <<= 1) {
    int x = (t >= off) ? sm[t - off] : 0;
    __syncthreads();
    sm[t] += x;
    __syncthreads();
  }
  int run = sm[t] - tsum;  // exclusive prefix of this thread within chunk
  if (base + 0 < N) excl[base + 0] = run; run += v0;
  if (base + 1 < N) excl[base + 1] = run; run += v1;
  if (base + 2 < N) excl[base + 2] = run; run += v2;
  if (base + 3 < N) excl[base + 3] = run;
  if (t == 255) bsum[blockIdx.x] = sm[255];
}

__global__ void scan2_k(int* __restrict__ bsum, int nb) {  // 1 block, 64 threads, nb <= 64
  int t = threadIdx.x;
  int orig = (t < nb) ? bsum[t] : 0;
  int v = orig;
  for (int off = 1; off < 64; off <<= 1) {
    int x = __shfl_up(v, off);
    if (t >= off) v += x;
  }
  if (t < nb) bsum[t] = v - orig;  // exclusive
}

__global__ void scan3_k(const int* __restrict__ excl, const int* __restrict__ bsum,
                        int* __restrict__ rowptr, int* __restrict__ wptr, int N, int E2) {
  int i = blockIdx.x * 256 + threadIdx.x;
  if (i < N) {
    int r = excl[i] + bsum[i >> 10];
    rowptr[i] = r;
    wptr[i] = r;
  }
  if (i == N) rowptr[N] = E2;
}

__global__ void scatter_k(const int* __restrict__ ei, int E, int E2,
                          int* __restrict__ wptr, int* __restrict__ csr_src) {
  int i = blockIdx.x * 256 + threadIdx.x;
  if (i >= E2) return;
  int s, d;
  if (i < E) { s = ei[i]; d = ei[E + i]; }
  else       { s = d = i - E; }
  int pos = atomicAdd(&wptr[d], 1);
  csr_src[pos] = s;
}

// ---------------- GEMM f32: C[M,N] = A[M,K] @ B[K,N]; N,K multiples of 16/64 ----------------

__global__ __launch_bounds__(256) void gemm_f32(const float* __restrict__ A,
                                                const float* __restrict__ B,
                                                float* __restrict__ C,
                                                int M, int N, int K) {
  __shared__ float As[16][68];  // transposed: As[k][m], +4 pad keeps float4 align & no conflicts
  __shared__ float Bs[16][68];
  int tid = threadIdx.x;
  int bm = blockIdx.y * 64;
  int bn = blockIdx.x * 64;
  int tx = tid & 15, ty = tid >> 4;
  int lr = tid >> 2;           // A row in tile 0..63
  int lk = (tid & 3) << 2;     // A k 0,4,8,12
  int bkr = tid >> 4;          // B k row 0..15
  int bnn = (tid & 15) << 2;   // B col 0..60
  bool arow_ok = (bm + lr) < M;
  const float* Aptr = A + (size_t)(bm + lr) * K + lk;
  const float* Bptr = B + (size_t)bkr * N + bn + bnn;
  float acc[4][4] = {};
  for (int k0 = 0; k0 < K; k0 += 16) {
    float4 av = arow_ok ? *(const float4*)(Aptr + k0) : make_float4(0.f, 0.f, 0.f, 0.f);
    float4 bv = *(const float4*)(Bptr + (size_t)k0 * N);
    As[lk + 0][lr] = av.x; As[lk + 1][lr] = av.y; As[lk + 2][lr] = av.z; As[lk + 3][lr] = av.w;
    *(float4*)&Bs[bkr][bnn] = bv;
    __syncthreads();
#pragma unroll
    for (int kk = 0; kk < 16; ++kk) {
      float4 a = *(const float4*)&As[kk][ty * 4];
      float4 b = *(const float4*)&Bs[kk][tx * 4];
      acc[0][0] = fmaf(a.x, b.x, acc[0][0]); acc[0][1] = fmaf(a.x, b.y, acc[0][1]);
      acc[0][2] = fmaf(a.x, b.z, acc[0][2]); acc[0][3] = fmaf(a.x, b.w, acc[0][3]);
      acc[1][0] = fmaf(a.y, b.x, acc[1][0]); acc[1][1] = fmaf(a.y, b.y, acc[1][1]);
      acc[1][2] = fmaf(a.y, b.z, acc[1][2]); acc[1][3] = fmaf(a.y, b.w, acc[1][3]);
      acc[2][0] = fmaf(a.z, b.x, acc[2][0]); acc[2][1] = fmaf(a.z, b.y, acc[2][1]);
      acc[2][2] = fmaf(a.z, b.z, acc[2][2]); acc[2][3] = fmaf(a.z, b.w, acc[2][3]);
      acc[3][0] = fmaf(a.w, b.x, acc[3][0]); acc[3][1] = fmaf(a.w, b.y, acc[3][1]);
      acc[3][2] = fmaf(a.w, b.z, acc[3][2]); acc[3][3] = fmaf(a.w, b.w, acc[3][3]);
    }
    __syncthreads();
  }
#pragma unroll
  for (int i = 0; i < 4; ++i) {
    int r = bm + ty * 4 + i;
    if (r < M) {
#pragma unroll
      for (int j = 0; j < 4; ++j) C[(size_t)r * N + bn + tx * 4 + j] = acc[i][j];
    }
  }
}

// ---------------- per-(node,head) attention coefficients ----------------
// a_src[n*H+h] = sum_c xw[n,h,c]*att_src[h,c];  a_dst likewise
__global__ void att_k(const float* __restrict__ xw, const float* __restrict__ att_s,
                      const float* __restrict__ att_d, float* __restrict__ a_s,
                      float* __restrict__ a_d, int NH, int H) {
  int wid = blockIdx.x * (blockDim.x >> 6) + (threadIdx.x >> 6);
  int lane = threadIdx.x & 63;
  if (wid >= NH) return;
  int h = wid % H;
  float x = xw[(size_t)wid * 64 + lane];
  float vs = x * att_s[h * 64 + lane];
  float vd = x * att_d[h * 64 + lane];
  for (int off = 32; off; off >>= 1) {
    vs += __shfl_xor(vs, off);
    vd += __shfl_xor(vd, off);
  }
  if (lane == 0) { a_s[wid] = vs; a_d[wid] = vd; }
}

// ---------------- per-dst-node online-softmax aggregation ----------------
// One wave handles one (node, head). lane = channel. act: 1 = ELU, 0 = none.
template <int H, int WPB>
__global__ __launch_bounds__(64 * H * WPB) void agg_k(
    const float* __restrict__ xw, const float* __restrict__ a_s,
    const float* __restrict__ a_d, const int* __restrict__ rowptr,
    const int* __restrict__ csr_src, const float* __restrict__ bias,
    float* __restrict__ hout, int N, int act) {
  constexpr int NW = H * WPB;
  __shared__ float pbuf[NW][64];
  __shared__ int sbuf[NW][64];
  int w = threadIdx.x >> 6;
  int lane = threadIdx.x & 63;
  int n = blockIdx.x * WPB + w / H;
  int h = w % H;
  if (n >= N) return;
  int beg = rowptr[n], end = rowptr[n + 1];
  float ad = a_d[n * H + h];
  float m = -INFINITY, ssum = 0.f, acc = 0.f;
  for (int c0 = beg; c0 < end; c0 += 64) {
    int cnt = min(64, end - c0);
    float ee = -INFINITY;
    int sidx = 0;
    if (lane < cnt) {
      sidx = csr_src[c0 + lane];
      float e = a_s[sidx * H + h] + ad;
      ee = (e > 0.f) ? e : NEG_SLOPE * e;
    }
    float cm = wave_max64(ee);
    float mnew = fmaxf(m, cm);
    float scale = __expf(m - mnew);  // m=-inf first chunk -> 0, acc/ssum are 0
    acc *= scale;
    ssum *= scale;
    m = mnew;
    float p = (lane < cnt) ? __expf(ee - m) : 0.f;
    ssum += wave_sum64(p);
    pbuf[w][lane] = p;
    sbuf[w][lane] = sidx;
    // wave-coherent LDS: no barrier needed (single-wave producer/consumer)
    for (int j = 0; j < cnt; ++j) {
      float pj = pbuf[w][j];
      int sj = sbuf[w][j];
      acc = fmaf(pj, xw[(size_t)sj * (H * 64) + h * 64 + lane], acc);
    }
  }
  float o = acc / ssum + bias[h * 64 + lane];
  if (act) o = (o > 0.f) ? o : __expf(o) - 1.f;  // ELU(alpha=1)
  hout[(size_t)n * (H * 64) + h * 64 + lane] = o;
}

// ---------------- final mean over nodes + classifier ----------------

__global__ void reduce_mean_k(const float* __restrict__ h3, float* __restrict__ g, int N) {
  __shared__ float sm[4][64];
  int w = threadIdx.x >> 6;
  int lane = threadIdx.x & 63;
  float acc = 0.f;
  for (int n = blockIdx.x * 4 + w; n < N; n += gridDim.x * 4)
    acc += h3[(size_t)n * 64 + lane];
  sm[w][lane] = acc;
  __syncthreads();
  if (w == 0) {
    float t = sm[0][lane] + sm[1][lane] + sm[2][lane] + sm[3][lane];
    atomicAdd(&g[lane], t);
  }
}

__global__ void final_k(const float* __restrict__ g, const float* __restrict__ Wc,
                        const float* __restrict__ bc, float* __restrict__ out, int N) {
  int lane = threadIdx.x;  // 64
  float gc = g[lane] / (float)N;  // b3 already folded in during agg3
  for (int j = 0; j < 10; ++j) {
    float v = gc * Wc[lane * 10 + j];
    for (int off = 32; off; off >>= 1) v += __shfl_down(v, off);
    if (lane == 0) out[j] = v + bc[j];
  }
}

// ---------------- launch ----------------

extern "C" void kernel_launch(void* const* d_in, const int* in_sizes, int n_in,
                              void* d_out, int out_size, void* d_ws, size_t ws_size,
                              hipStream_t stream) {
  const float* x   = (const float*)d_in[0];
  const int*   ei  = (const int*)d_in[1];
  const float* W1  = (const float*)d_in[2];
  const float* as1 = (const float*)d_in[3];
  const float* ad1 = (const float*)d_in[4];
  const float* b1  = (const float*)d_in[5];
  const float* W2  = (const float*)d_in[6];
  const float* as2 = (const float*)d_in[7];
  const float* ad2 = (const float*)d_in[8];
  const float* b2  = (const float*)d_in[9];
  const float* W3  = (const float*)d_in[10];
  const float* as3 = (const float*)d_in[11];
  const float* ad3 = (const float*)d_in[12];
  const float* b3  = (const float*)d_in[13];
  const float* Wc  = (const float*)d_in[14];
  const float* bc  = (const float*)d_in[15];
  float* out = (float*)d_out;

  int N = in_sizes[0] / 128;
  int E = in_sizes[1] / 2;
  int E2 = E + N;

  char* w = (char*)d_ws;
  auto alloc = [&](size_t bytes) {
    char* p = w;
    w += (bytes + 255) & ~(size_t)255;
    return p;
  };
  float* bufA   = (float*)alloc((size_t)N * 256 * 4);
  float* bufB   = (float*)alloc((size_t)N * 256 * 4);
  float* a_s    = (float*)alloc((size_t)N * 4 * 4);
  float* a_d    = (float*)alloc((size_t)N * 4 * 4);
  int*   deg    = (int*)alloc((size_t)N * 4);
  int*   excl   = (int*)alloc((size_t)N * 4);
  int*   bsum   = (int*)alloc(64 * 4);
  int*   rowptr = (int*)alloc((size_t)(N + 1) * 4);
  int*   wptr   = (int*)alloc((size_t)N * 4);
  int*   csr    = (int*)alloc((size_t)E2 * 4);
  float* g      = (float*)alloc(64 * 4);

  hipMemsetAsync(deg, 0, (size_t)N * 4, stream);
  hipMemsetAsync(g, 0, 64 * 4, stream);

  int gE2 = (E2 + 255) / 256;
  hist_k<<<gE2, 256, 0, stream>>>(ei, E, E2, deg);
  int nb = (N + 1023) / 1024;
  scan1_k<<<nb, 256, 0, stream>>>(deg, excl, bsum, N);
  scan2_k<<<1, 64, 0, stream>>>(bsum, nb);
  scan3_k<<<(N + 256) / 256, 256, 0, stream>>>(excl, bsum, rowptr, wptr, N, E2);
  scatter_k<<<gE2, 256, 0, stream>>>(ei, E, E2, wptr, csr);

  int mb = (N + 63) / 64;
  // layer 1: x[N,128] @ W1[128,256]
  gemm_f32<<<dim3(4, mb), 256, 0, stream>>>(x, W1, bufA, N, 256, 128);
  att_k<<<(N * 4 + 3) / 4, 256, 0, stream>>>(bufA, as1, ad1, a_s, a_d, N * 4, 4);
  agg_k<4, 1><<<N, 256, 0, stream>>>(bufA, a_s, a_d, rowptr, csr, b1, bufB, N, 1);
  // layer 2: h1[N,256] @ W2[256,256]
  gemm_f32<<<dim3(4, mb), 256, 0, stream>>>(bufB, W2, bufA, N, 256, 256);
  att_k<<<(N * 4 + 3) / 4, 256, 0, stream>>>(bufA, as2, ad2, a_s, a_d, N * 4, 4);
  agg_k<4, 1><<<N, 256, 0, stream>>>(bufA, a_s, a_d, rowptr, csr, b2, bufB, N, 1);
  // layer 3: h2[N,256] @ W3[256,64], single head
  gemm_f32<<<dim3(1, mb), 256, 0, stream>>>(bufB, W3, bufA, N, 64, 256);
  att_k<<<(N + 3) / 4, 256, 0, stream>>>(bufA, as3, ad3, a_s, a_d, N, 1);
  agg_k<1, 4><<<(N + 3) / 4, 256, 0, stream>>>(bufA, a_s, a_d, rowptr, csr, b3, bufB, N, 0);

  reduce_mean_k<<<256, 256, 0, stream>>>(bufB, g, N);
  final_k<<<1, 64, 0, stream>>>(g, Wc, bc, out, N);
}

// Round 4
// 608.136 us; speedup vs baseline: 1.2653x; 1.2653x over previous
//
#include <hip/hip_runtime.h>

#define NEG_SLOPE 0.2f

typedef __attribute__((ext_vector_type(8))) short bf16x8;
typedef __attribute__((ext_vector_type(4))) float f32x4;

__device__ __forceinline__ float bf2f(ushort u) {
  return __uint_as_float(((unsigned int)u) << 16);
}
__device__ __forceinline__ ushort f2bf(float f) {  // round-to-nearest-even
  unsigned int u = __float_as_uint(f);
  u += 0x7fff + ((u >> 16) & 1);
  return (ushort)(u >> 16);
}

__device__ __forceinline__ float wave_max64(float v) {
  for (int off = 32; off; off >>= 1) v = fmaxf(v, __shfl_xor(v, off));
  return v;
}
__device__ __forceinline__ float wave_sum64(float v) {
  for (int off = 32; off; off >>= 1) v += __shfl_xor(v, off);
  return v;
}

// ---------------- CSR build ----------------

__global__ void hist_k(const int* __restrict__ ei, int E, int E2, int* __restrict__ deg) {
  int i = blockIdx.x * 256 + threadIdx.x;
  if (i >= E2) return;
  int d = (i < E) ? ei[E + i] : (i - E);
  atomicAdd(&deg[d], 1);
}

__global__ void scan1_k(const int* __restrict__ deg, int* __restrict__ excl,
                        int* __restrict__ bsum, int N) {
  __shared__ int sm[256];
  int t = threadIdx.x;
  int base = blockIdx.x * 1024 + t * 4;
  int v0 = (base + 0 < N) ? deg[base + 0] : 0;
  int v1 = (base + 1 < N) ? deg[base + 1] : 0;
  int v2 = (base + 2 < N) ? deg[base + 2] : 0;
  int v3 = (base + 3 < N) ? deg[base + 3] : 0;
  int tsum = v0 + v1 + v2 + v3;
  sm[t] = tsum;
  __syncthreads();
  for (int off = 1; off < 256; off <<= 1) {
    int x = (t >= off) ? sm[t - off] : 0;
    __syncthreads();
    sm[t] += x;
    __syncthreads();
  }
  int run = sm[t] - tsum;
  if (base + 0 < N) excl[base + 0] = run; run += v0;
  if (base + 1 < N) excl[base + 1] = run; run += v1;
  if (base + 2 < N) excl[base + 2] = run; run += v2;
  if (base + 3 < N) excl[base + 3] = run;
  if (t == 255) bsum[blockIdx.x] = sm[255];
}

__global__ void scan2_k(int* __restrict__ bsum, int nb) {
  int t = threadIdx.x;
  int orig = (t < nb) ? bsum[t] : 0;
  int v = orig;
  for (int off = 1; off < 64; off <<= 1) {
    int x = __shfl_up(v, off);
    if (t >= off) v += x;
  }
  if (t < nb) bsum[t] = v - orig;
}

__global__ void scan3_k(const int* __restrict__ excl, const int* __restrict__ bsum,
                        int* __restrict__ rowptr, int* __restrict__ wptr, int N, int E2) {
  int i = blockIdx.x * 256 + threadIdx.x;
  if (i < N) {
    int r = excl[i] + bsum[i >> 10];
    rowptr[i] = r;
    wptr[i] = r;
  }
  if (i == N) rowptr[N] = E2;
}

__global__ void scatter_k(const int* __restrict__ ei, int E, int E2,
                          int* __restrict__ wptr, int* __restrict__ csr_src) {
  int i = blockIdx.x * 256 + threadIdx.x;
  if (i >= E2) return;
  int s, d;
  if (i < E) { s = ei[i]; d = ei[E + i]; }
  else       { s = d = i - E; }
  int pos = atomicAdd(&wptr[d], 1);
  csr_src[pos] = s;
}

// ---------------- conversions ----------------

__global__ void f2b_k(const float* __restrict__ in, ushort* __restrict__ out, int n4) {
  int i = blockIdx.x * 256 + threadIdx.x;
  if (i >= n4) return;
  float4 v = ((const float4*)in)[i];
  ushort4 o;
  o.x = f2bf(v.x); o.y = f2bf(v.y); o.z = f2bf(v.z); o.w = f2bf(v.w);
  ((ushort4*)out)[i] = o;
}

// W[K][Nc] f32 -> Wt[Nc][K] bf16
__global__ void wtrans_k(const float* __restrict__ W, ushort* __restrict__ Wt, int K, int Nc) {
  int k = blockIdx.x * 16 + (threadIdx.x & 15);
  int n = blockIdx.y * 16 + (threadIdx.x >> 4);
  if (k < K && n < Nc) Wt[(size_t)n * K + k] = f2bf(W[(size_t)k * Nc + n]);
}

// ---------------- bf16 MFMA GEMM: C[M,N]=A[M,K]@B[K,N], Bt[N][K] input ----------------
// BM=64, BN=64, BK=32; 256 threads = 4 waves; wave w -> rows [bm+16w, bm+16w+16)

__global__ __launch_bounds__(256) void gemm_bf16(const ushort* __restrict__ A,
                                                 const ushort* __restrict__ Bt,
                                                 ushort* __restrict__ C,
                                                 int M, int N, int K) {
  __shared__ ushort As[64][40];  // +8 pad: stage writes 2-way, frag reads ~2-way conflicts
  __shared__ ushort Bs[64][40];
  int tid = threadIdx.x;
  int w = tid >> 6, l = tid & 63;
  int bm = blockIdx.y * 64, bn = blockIdx.x * 64;
  int srow = tid >> 2, sseg = (tid & 3) * 8;
  bool aok = (bm + srow) < M;
  const ushort* Ap = A + (size_t)(bm + srow) * K + sseg;
  const ushort* Bp = Bt + (size_t)(bn + srow) * K + sseg;  // bn+srow < N always (N%64==0)
  f32x4 acc[4];
#pragma unroll
  for (int nb = 0; nb < 4; ++nb) acc[nb] = (f32x4){0.f, 0.f, 0.f, 0.f};
  int fr = l & 15, fk = (l >> 4) * 8;
  for (int k0 = 0; k0 < K; k0 += 32) {
    bf16x8 av = {0, 0, 0, 0, 0, 0, 0, 0};
    if (aok) av = *(const bf16x8*)(Ap + k0);
    bf16x8 bv = *(const bf16x8*)(Bp + k0);
    *(bf16x8*)&As[srow][sseg] = av;
    *(bf16x8*)&Bs[srow][sseg] = bv;
    __syncthreads();
    bf16x8 af = *(bf16x8*)&As[16 * w + fr][fk];
#pragma unroll
    for (int nb = 0; nb < 4; ++nb) {
      bf16x8 bfv = *(bf16x8*)&Bs[nb * 16 + fr][fk];
      acc[nb] = __builtin_amdgcn_mfma_f32_16x16x32_bf16(af, bfv, acc[nb], 0, 0, 0);
    }
    __syncthreads();
  }
  int fg = l >> 4;
#pragma unroll
  for (int nb = 0; nb < 4; ++nb)
#pragma unroll
    for (int r = 0; r < 4; ++r) {
      int row = bm + 16 * w + fg * 4 + r;
      if (row < M) C[(size_t)row * N + bn + nb * 16 + fr] = f2bf(acc[nb][r]);
    }
}

// ---------------- per-(node,head) attention coefficients ----------------

__global__ void att_k(const ushort* __restrict__ xw, const float* __restrict__ att_s,
                      const float* __restrict__ att_d, float* __restrict__ a_s,
                      float* __restrict__ a_d, int NH, int H) {
  int wid = blockIdx.x * (blockDim.x >> 6) + (threadIdx.x >> 6);
  int lane = threadIdx.x & 63;
  if (wid >= NH) return;
  int h = wid % H;
  float x = bf2f(xw[(size_t)wid * 64 + lane]);
  float vs = x * att_s[h * 64 + lane];
  float vd = x * att_d[h * 64 + lane];
  for (int off = 32; off; off >>= 1) {
    vs += __shfl_xor(vs, off);
    vd += __shfl_xor(vd, off);
  }
  if (lane == 0) { a_s[wid] = vs; a_d[wid] = vd; }
}

// ---------------- per-dst-node online-softmax aggregation ----------------

template <int H, int WPB, int OUTBF>
__global__ __launch_bounds__(64 * H * WPB) void agg_k(
    const ushort* __restrict__ xw, const float* __restrict__ a_s,
    const float* __restrict__ a_d, const int* __restrict__ rowptr,
    const int* __restrict__ csr_src, const float* __restrict__ bias,
    void* __restrict__ hout, int N, int act) {
  constexpr int NW = H * WPB;
  __shared__ float pbuf[NW][64];
  __shared__ int sbuf[NW][64];
  int w = threadIdx.x >> 6;
  int lane = threadIdx.x & 63;
  int n = blockIdx.x * WPB + w / H;
  int h = w % H;
  if (n >= N) return;
  int beg = rowptr[n], end = rowptr[n + 1];
  float ad = a_d[n * H + h];
  float m = -INFINITY, ssum = 0.f, acc = 0.f;
  for (int c0 = beg; c0 < end; c0 += 64) {
    int cnt = min(64, end - c0);
    float ee = -INFINITY;
    int sidx = 0;
    if (lane < cnt) {
      sidx = csr_src[c0 + lane];
      float e = a_s[sidx * H + h] + ad;
      ee = (e > 0.f) ? e : NEG_SLOPE * e;
    }
    float cm = wave_max64(ee);
    float mnew = fmaxf(m, cm);
    float scale = __expf(m - mnew);
    acc *= scale;
    ssum *= scale;
    m = mnew;
    float p = (lane < cnt) ? __expf(ee - m) : 0.f;
    ssum += wave_sum64(p);
    pbuf[w][lane] = p;
    sbuf[w][lane] = sidx;
    // single-wave producer/consumer LDS: in-order, no barrier
    for (int j = 0; j < cnt; ++j) {
      float pj = pbuf[w][j];
      int sj = sbuf[w][j];
      acc = fmaf(pj, bf2f(xw[(size_t)sj * (H * 64) + h * 64 + lane]), acc);
    }
  }
  float o = acc / ssum + bias[h * 64 + lane];
  if (act) o = (o > 0.f) ? o : __expf(o) - 1.f;  // ELU
  if (OUTBF)
    ((ushort*)hout)[(size_t)n * (H * 64) + h * 64 + lane] = f2bf(o);
  else
    ((float*)hout)[(size_t)n * (H * 64) + h * 64 + lane] = o;
}

// ---------------- final mean over nodes + classifier ----------------

__global__ void reduce_mean_k(const float* __restrict__ h3, float* __restrict__ g, int N) {
  __shared__ float sm[4][64];
  int w = threadIdx.x >> 6;
  int lane = threadIdx.x & 63;
  float acc = 0.f;
  for (int n = blockIdx.x * 4 + w; n < N; n += gridDim.x * 4)
    acc += h3[(size_t)n * 64 + lane];
  sm[w][lane] = acc;
  __syncthreads();
  if (w == 0) {
    float t = sm[0][lane] + sm[1][lane] + sm[2][lane] + sm[3][lane];
    atomicAdd(&g[lane], t);
  }
}

__global__ void final_k(const float* __restrict__ g, const float* __restrict__ Wc,
                        const float* __restrict__ bc, float* __restrict__ out, int N) {
  int lane = threadIdx.x;  // 64
  float gc = g[lane] / (float)N;
  for (int j = 0; j < 10; ++j) {
    float v = gc * Wc[lane * 10 + j];
    for (int off = 32; off; off >>= 1) v += __shfl_down(v, off);
    if (lane == 0) out[j] = v + bc[j];
  }
}

// ---------------- launch ----------------

extern "C" void kernel_launch(void* const* d_in, const int* in_sizes, int n_in,
                              void* d_out, int out_size, void* d_ws, size_t ws_size,
                              hipStream_t stream) {
  const float* x   = (const float*)d_in[0];
  const int*   ei  = (const int*)d_in[1];
  const float* W1  = (const float*)d_in[2];
  const float* as1 = (const float*)d_in[3];
  const float* ad1 = (const float*)d_in[4];
  const float* b1  = (const float*)d_in[5];
  const float* W2  = (const float*)d_in[6];
  const float* as2 = (const float*)d_in[7];
  const float* ad2 = (const float*)d_in[8];
  const float* b2  = (const float*)d_in[9];
  const float* W3  = (const float*)d_in[10];
  const float* as3 = (const float*)d_in[11];
  const float* ad3 = (const float*)d_in[12];
  const float* b3  = (const float*)d_in[13];
  const float* Wc  = (const float*)d_in[14];
  const float* bc  = (const float*)d_in[15];
  float* out = (float*)d_out;

  int N = in_sizes[0] / 128;
  int E = in_sizes[1] / 2;
  int E2 = E + N;

  char* w = (char*)d_ws;
  auto alloc = [&](size_t bytes) {
    char* p = w;
    w += (bytes + 255) & ~(size_t)255;
    return p;
  };
  ushort* xb   = (ushort*)alloc((size_t)N * 128 * 2);
  ushort* xwb  = (ushort*)alloc((size_t)N * 256 * 2);
  ushort* hb   = (ushort*)alloc((size_t)N * 256 * 2);
  float*  h3f  = (float*)alloc((size_t)N * 64 * 4);
  ushort* w1t  = (ushort*)alloc((size_t)256 * 128 * 2);
  ushort* w2t  = (ushort*)alloc((size_t)256 * 256 * 2);
  ushort* w3t  = (ushort*)alloc((size_t)64 * 256 * 2);
  float*  a_s  = (float*)alloc((size_t)N * 4 * 4);
  float*  a_d  = (float*)alloc((size_t)N * 4 * 4);
  int*   deg    = (int*)alloc((size_t)N * 4);
  int*   excl   = (int*)alloc((size_t)N * 4);
  int*   bsum   = (int*)alloc(64 * 4);
  int*   rowptr = (int*)alloc((size_t)(N + 1) * 4);
  int*   wptr   = (int*)alloc((size_t)N * 4);
  int*   csr    = (int*)alloc((size_t)E2 * 4);
  float* g      = (float*)alloc(64 * 4);

  hipMemsetAsync(deg, 0, (size_t)N * 4, stream);
  hipMemsetAsync(g, 0, 64 * 4, stream);

  // conversions
  f2b_k<<<(N * 128 / 4 + 255) / 256, 256, 0, stream>>>(x, xb, N * 128 / 4);
  wtrans_k<<<dim3(8, 16), 256, 0, stream>>>(W1, w1t, 128, 256);
  wtrans_k<<<dim3(16, 16), 256, 0, stream>>>(W2, w2t, 256, 256);
  wtrans_k<<<dim3(16, 4), 256, 0, stream>>>(W3, w3t, 256, 64);

  // CSR
  int gE2 = (E2 + 255) / 256;
  hist_k<<<gE2, 256, 0, stream>>>(ei, E, E2, deg);
  int nb = (N + 1023) / 1024;
  scan1_k<<<nb, 256, 0, stream>>>(deg, excl, bsum, N);
  scan2_k<<<1, 64, 0, stream>>>(bsum, nb);
  scan3_k<<<(N + 256) / 256, 256, 0, stream>>>(excl, bsum, rowptr, wptr, N, E2);
  scatter_k<<<gE2, 256, 0, stream>>>(ei, E, E2, wptr, csr);

  int mb = (N + 63) / 64;
  // layer 1: xb[N,128] @ W1 -> xwb[N,256]
  gemm_bf16<<<dim3(4, mb), 256, 0, stream>>>(xb, w1t, xwb, N, 256, 128);
  att_k<<<(N * 4 + 3) / 4, 256, 0, stream>>>(xwb, as1, ad1, a_s, a_d, N * 4, 4);
  agg_k<4, 1, 1><<<N, 256, 0, stream>>>(xwb, a_s, a_d, rowptr, csr, b1, hb, N, 1);
  // layer 2: hb[N,256] @ W2 -> xwb[N,256]
  gemm_bf16<<<dim3(4, mb), 256, 0, stream>>>(hb, w2t, xwb, N, 256, 256);
  att_k<<<(N * 4 + 3) / 4, 256, 0, stream>>>(xwb, as2, ad2, a_s, a_d, N * 4, 4);
  agg_k<4, 1, 1><<<N, 256, 0, stream>>>(xwb, a_s, a_d, rowptr, csr, b2, hb, N, 1);
  // layer 3: hb[N,256] @ W3 -> xwb[N,64] (single head)
  gemm_bf16<<<dim3(1, mb), 256, 0, stream>>>(hb, w3t, xwb, N, 64, 256);
  att_k<<<(N + 3) / 4, 256, 0, stream>>>(xwb, as3, ad3, a_s, a_d, N, 1);
  agg_k<1, 4, 0><<<(N + 3) / 4, 256, 0, stream>>>(xwb, a_s, a_d, rowptr, csr, b3, h3f, N, 0);

  reduce_mean_k<<<256, 256, 0, stream>>>(h3f, g, N);
  final_k<<<1, 64, 0, stream>>>(g, Wc, bc, out, N);
}

// Round 5
// 529.169 us; speedup vs baseline: 1.4541x; 1.1492x over previous
//
#include <hip/hip_runtime.h>

#define NEG_SLOPE 0.2f

typedef __attribute__((ext_vector_type(8))) short bf16x8;
typedef __attribute__((ext_vector_type(4))) float f32x4;

__device__ __forceinline__ float bf2f(ushort u) {
  return __uint_as_float(((unsigned int)u) << 16);
}
__device__ __forceinline__ ushort f2bf(float f) {  // round-to-nearest-even
  unsigned int u = __float_as_uint(f);
  u += 0x7fff + ((u >> 16) & 1);
  return (ushort)(u >> 16);
}

__device__ __forceinline__ float wave_max64(float v) {
  for (int off = 32; off; off >>= 1) v = fmaxf(v, __shfl_xor(v, off));
  return v;
}
__device__ __forceinline__ float wave_sum64(float v) {
  for (int off = 32; off; off >>= 1) v += __shfl_xor(v, off);
  return v;
}

// ---------------- CSR build ----------------

__global__ void hist_k(const int* __restrict__ ei, int E, int E2, int* __restrict__ deg) {
  int i = blockIdx.x * 256 + threadIdx.x;
  if (i >= E2) return;
  int d = (i < E) ? ei[E + i] : (i - E);
  atomicAdd(&deg[d], 1);
}

__global__ void scan1_k(const int* __restrict__ deg, int* __restrict__ excl,
                        int* __restrict__ bsum, int N) {
  __shared__ int sm[256];
  int t = threadIdx.x;
  int base = blockIdx.x * 1024 + t * 4;
  int v0 = (base + 0 < N) ? deg[base + 0] : 0;
  int v1 = (base + 1 < N) ? deg[base + 1] : 0;
  int v2 = (base + 2 < N) ? deg[base + 2] : 0;
  int v3 = (base + 3 < N) ? deg[base + 3] : 0;
  int tsum = v0 + v1 + v2 + v3;
  sm[t] = tsum;
  __syncthreads();
  for (int off = 1; off < 256; off <<= 1) {
    int x = (t >= off) ? sm[t - off] : 0;
    __syncthreads();
    sm[t] += x;
    __syncthreads();
  }
  int run = sm[t] - tsum;
  if (base + 0 < N) excl[base + 0] = run; run += v0;
  if (base + 1 < N) excl[base + 1] = run; run += v1;
  if (base + 2 < N) excl[base + 2] = run; run += v2;
  if (base + 3 < N) excl[base + 3] = run;
  if (t == 255) bsum[blockIdx.x] = sm[255];
}

__global__ void scan2_k(int* __restrict__ bsum, int nb) {
  int t = threadIdx.x;
  int orig = (t < nb) ? bsum[t] : 0;
  int v = orig;
  for (int off = 1; off < 64; off <<= 1) {
    int x = __shfl_up(v, off);
    if (t >= off) v += x;
  }
  if (t < nb) bsum[t] = v - orig;
}

__global__ void scan3_k(const int* __restrict__ excl, const int* __restrict__ bsum,
                        int* __restrict__ rowptr, int* __restrict__ wptr, int N, int E2) {
  int i = blockIdx.x * 256 + threadIdx.x;
  if (i < N) {
    int r = excl[i] + bsum[i >> 10];
    rowptr[i] = r;
    wptr[i] = r;
  }
  if (i == N) rowptr[N] = E2;
}

__global__ void scatter_k(const int* __restrict__ ei, int E, int E2,
                          int* __restrict__ wptr, int* __restrict__ csr_src) {
  int i = blockIdx.x * 256 + threadIdx.x;
  if (i >= E2) return;
  int s, d;
  if (i < E) { s = ei[i]; d = ei[E + i]; }
  else       { s = d = i - E; }
  int pos = atomicAdd(&wptr[d], 1);
  csr_src[pos] = s;
}

// ---------------- conversions ----------------

__global__ void f2b_k(const float* __restrict__ in, ushort* __restrict__ out, int n4) {
  int i = blockIdx.x * 256 + threadIdx.x;
  if (i >= n4) return;
  float4 v = ((const float4*)in)[i];
  ushort4 o;
  o.x = f2bf(v.x); o.y = f2bf(v.y); o.z = f2bf(v.z); o.w = f2bf(v.w);
  ((ushort4*)out)[i] = o;
}

// W[K][Nc] f32 -> Wt[Nc][K] bf16
__global__ void wtrans_k(const float* __restrict__ W, ushort* __restrict__ Wt, int K, int Nc) {
  int k = blockIdx.x * 16 + (threadIdx.x & 15);
  int n = blockIdx.y * 16 + (threadIdx.x >> 4);
  if (k < K && n < Nc) Wt[(size_t)n * K + k] = f2bf(W[(size_t)k * Nc + n]);
}

// ---------------- bf16 MFMA GEMM: C[M,N]=A[M,K]@B[K,N], Bt[N][K] input ----------------

__global__ __launch_bounds__(256) void gemm_bf16(const ushort* __restrict__ A,
                                                 const ushort* __restrict__ Bt,
                                                 ushort* __restrict__ C,
                                                 int M, int N, int K) {
  __shared__ ushort As[64][40];
  __shared__ ushort Bs[64][40];
  int tid = threadIdx.x;
  int w = tid >> 6, l = tid & 63;
  int bm = blockIdx.y * 64, bn = blockIdx.x * 64;
  int srow = tid >> 2, sseg = (tid & 3) * 8;
  bool aok = (bm + srow) < M;
  const ushort* Ap = A + (size_t)(bm + srow) * K + sseg;
  const ushort* Bp = Bt + (size_t)(bn + srow) * K + sseg;
  f32x4 acc[4];
#pragma unroll
  for (int nb = 0; nb < 4; ++nb) acc[nb] = (f32x4){0.f, 0.f, 0.f, 0.f};
  int fr = l & 15, fk = (l >> 4) * 8;
  for (int k0 = 0; k0 < K; k0 += 32) {
    bf16x8 av = {0, 0, 0, 0, 0, 0, 0, 0};
    if (aok) av = *(const bf16x8*)(Ap + k0);
    bf16x8 bv = *(const bf16x8*)(Bp + k0);
    *(bf16x8*)&As[srow][sseg] = av;
    *(bf16x8*)&Bs[srow][sseg] = bv;
    __syncthreads();
    bf16x8 af = *(bf16x8*)&As[16 * w + fr][fk];
#pragma unroll
    for (int nb = 0; nb < 4; ++nb) {
      bf16x8 bfv = *(bf16x8*)&Bs[nb * 16 + fr][fk];
      acc[nb] = __builtin_amdgcn_mfma_f32_16x16x32_bf16(af, bfv, acc[nb], 0, 0, 0);
    }
    __syncthreads();
  }
  int fg = l >> 4;
#pragma unroll
  for (int nb = 0; nb < 4; ++nb)
#pragma unroll
    for (int r = 0; r < 4; ++r) {
      int row = bm + 16 * w + fg * 4 + r;
      if (row < M) C[(size_t)row * N + bn + nb * 16 + fr] = f2bf(acc[nb][r]);
    }
}

// ---------------- per-(node,head) attention coefficients ----------------

__global__ void att_k(const ushort* __restrict__ xw, const float* __restrict__ att_s,
                      const float* __restrict__ att_d, float* __restrict__ a_s,
                      float* __restrict__ a_d, int NH, int H) {
  int wid = blockIdx.x * (blockDim.x >> 6) + (threadIdx.x >> 6);
  int lane = threadIdx.x & 63;
  if (wid >= NH) return;
  int h = wid % H;
  float x = bf2f(xw[(size_t)wid * 64 + lane]);
  float vs = x * att_s[h * 64 + lane];
  float vd = x * att_d[h * 64 + lane];
  for (int off = 32; off; off >>= 1) {
    vs += __shfl_xor(vs, off);
    vd += __shfl_xor(vd, off);
  }
  if (lane == 0) { a_s[wid] = vs; a_d[wid] = vd; }
}

// ---------------- aggregation, H=4: wave = node, lane = (head, 4 channels) ----------------
// Per edge the wave reads the full 512B xw row with one ushort4/lane load.

template <int WPB, int ACT>
__global__ __launch_bounds__(64 * WPB) void agg4_k(
    const ushort* __restrict__ xw, const float4* __restrict__ a_s4,
    const float4* __restrict__ a_d4, const int* __restrict__ rowptr,
    const int* __restrict__ csr_src, const float* __restrict__ bias,
    ushort* __restrict__ hout, int N) {
  __shared__ float pbuf[WPB][4][66];  // [head][edge], +2 pad -> broadcast reads conflict-free
  __shared__ int sbuf[WPB][64];
  int w = threadIdx.x >> 6, l = threadIdx.x & 63;
  int n = blockIdx.x * WPB + w;
  if (n >= N) return;
  int h = l >> 4;
  int beg = rowptr[n], end = rowptr[n + 1];
  float4 ad = a_d4[n];
  float m0 = -INFINITY, m1 = -INFINITY, m2 = -INFINITY, m3 = -INFINITY;
  float s0 = 0.f, s1 = 0.f, s2 = 0.f, s3 = 0.f;
  f32x4 acc = {0.f, 0.f, 0.f, 0.f};
  const ushort4* xw4 = (const ushort4*)xw;
  for (int c0 = beg; c0 < end; c0 += 64) {
    int cnt = min(64, end - c0);
    float e0 = -INFINITY, e1 = -INFINITY, e2 = -INFINITY, e3 = -INFINITY;
    int sidx = 0;
    if (l < cnt) {
      sidx = csr_src[c0 + l];
      float4 as = a_s4[sidx];
      e0 = as.x + ad.x; e0 = e0 > 0.f ? e0 : NEG_SLOPE * e0;
      e1 = as.y + ad.y; e1 = e1 > 0.f ? e1 : NEG_SLOPE * e1;
      e2 = as.z + ad.z; e2 = e2 > 0.f ? e2 : NEG_SLOPE * e2;
      e3 = as.w + ad.w; e3 = e3 > 0.f ? e3 : NEG_SLOPE * e3;
    }
    float n0 = fmaxf(m0, wave_max64(e0));
    float n1 = fmaxf(m1, wave_max64(e1));
    float n2 = fmaxf(m2, wave_max64(e2));
    float n3 = fmaxf(m3, wave_max64(e3));
    float sc0 = __expf(m0 - n0), sc1 = __expf(m1 - n1);
    float sc2 = __expf(m2 - n2), sc3 = __expf(m3 - n3);
    s0 *= sc0; s1 *= sc1; s2 *= sc2; s3 *= sc3;
    m0 = n0; m1 = n1; m2 = n2; m3 = n3;
    float p0 = __expf(e0 - m0);  // e=-inf -> 0
    float p1 = __expf(e1 - m1);
    float p2 = __expf(e2 - m2);
    float p3 = __expf(e3 - m3);
    s0 += wave_sum64(p0); s1 += wave_sum64(p1);
    s2 += wave_sum64(p2); s3 += wave_sum64(p3);
    pbuf[w][0][l] = p0; pbuf[w][1][l] = p1;
    pbuf[w][2][l] = p2; pbuf[w][3][l] = p3;
    sbuf[w][l] = sidx;
    float scmy = h == 0 ? sc0 : h == 1 ? sc1 : h == 2 ? sc2 : sc3;
    acc[0] *= scmy; acc[1] *= scmy; acc[2] *= scmy; acc[3] *= scmy;
    // single-wave LDS producer/consumer: in-order, no barrier
    for (int j = 0; j < cnt; ++j) {
      int sj = sbuf[w][j];
      float pj = pbuf[w][h][j];
      ushort4 v = xw4[sj * 64 + l];  // full 512B row per wave
      acc[0] = fmaf(pj, bf2f(v.x), acc[0]);
      acc[1] = fmaf(pj, bf2f(v.y), acc[1]);
      acc[2] = fmaf(pj, bf2f(v.z), acc[2]);
      acc[3] = fmaf(pj, bf2f(v.w), acc[3]);
    }
  }
  float smy = h == 0 ? s0 : h == 1 ? s1 : h == 2 ? s2 : s3;
  float inv = 1.f / smy;
  int cb = l * 4;  // == h*64 + (l&15)*4
  float o0 = acc[0] * inv + bias[cb + 0];
  float o1 = acc[1] * inv + bias[cb + 1];
  float o2 = acc[2] * inv + bias[cb + 2];
  float o3 = acc[3] * inv + bias[cb + 3];
  if (ACT) {
    o0 = o0 > 0.f ? o0 : __expf(o0) - 1.f;
    o1 = o1 > 0.f ? o1 : __expf(o1) - 1.f;
    o2 = o2 > 0.f ? o2 : __expf(o2) - 1.f;
    o3 = o3 > 0.f ? o3 : __expf(o3) - 1.f;
  }
  ushort4 ov;
  ov.x = f2bf(o0); ov.y = f2bf(o1); ov.z = f2bf(o2); ov.w = f2bf(o3);
  ((ushort4*)(hout + (size_t)n * 256))[l] = ov;
}

// ---------------- aggregation, H=1 (layer 3): 4 edges per iteration ----------------
// lane l -> edge-slot g=l>>4, channels q=(l&15)*4; final shfl-reduce across groups.

template <int WPB>
__global__ __launch_bounds__(64 * WPB) void agg1_k(
    const ushort* __restrict__ xw, const float* __restrict__ a_s,
    const float* __restrict__ a_d, const int* __restrict__ rowptr,
    const int* __restrict__ csr_src, const float* __restrict__ bias,
    float* __restrict__ hout, int N) {
  __shared__ float pbuf[WPB][64];
  __shared__ int sbuf[WPB][64];
  int w = threadIdx.x >> 6, l = threadIdx.x & 63;
  int n = blockIdx.x * WPB + w;
  if (n >= N) return;
  int g = l >> 4, q = l & 15;
  int beg = rowptr[n], end = rowptr[n + 1];
  float ad = a_d[n];
  float m = -INFINITY, ss = 0.f;
  f32x4 acc = {0.f, 0.f, 0.f, 0.f};
  const ushort4* xw4 = (const ushort4*)xw;
  for (int c0 = beg; c0 < end; c0 += 64) {
    int cnt = min(64, end - c0);
    float e = -INFINITY;
    int sidx = 0;
    if (l < cnt) {
      sidx = csr_src[c0 + l];
      float t = a_s[sidx] + ad;
      e = t > 0.f ? t : NEG_SLOPE * t;
    }
    float nmax = fmaxf(m, wave_max64(e));
    float sc = __expf(m - nmax);
    ss *= sc;
    m = nmax;
    acc[0] *= sc; acc[1] *= sc; acc[2] *= sc; acc[3] *= sc;
    float p = __expf(e - m);
    ss += wave_sum64(p);
    pbuf[w][l] = p;
    sbuf[w][l] = sidx;
    for (int j = 0; j < cnt; j += 4) {
      int jj = j + g;
      bool ok = jj < cnt;
      int idx = ok ? jj : 0;
      float pj = pbuf[w][idx];
      if (!ok) pj = 0.f;
      int sj = sbuf[w][idx];
      ushort4 v = xw4[sj * 16 + q];  // 4 rows of 128B read concurrently
      acc[0] = fmaf(pj, bf2f(v.x), acc[0]);
      acc[1] = fmaf(pj, bf2f(v.y), acc[1]);
      acc[2] = fmaf(pj, bf2f(v.z), acc[2]);
      acc[3] = fmaf(pj, bf2f(v.w), acc[3]);
    }
  }
#pragma unroll
  for (int i = 0; i < 4; ++i) {
    acc[i] += __shfl_xor(acc[i], 16);
    acc[i] += __shfl_xor(acc[i], 32);
  }
  float inv = 1.f / ss;
  float4 o;
  o.x = acc[0] * inv + bias[q * 4 + 0];
  o.y = acc[1] * inv + bias[q * 4 + 1];
  o.z = acc[2] * inv + bias[q * 4 + 2];
  o.w = acc[3] * inv + bias[q * 4 + 3];
  if (g == 0) ((float4*)(hout + (size_t)n * 64))[q] = o;
}

// ---------------- final mean over nodes + classifier ----------------

__global__ void reduce_mean_k(const float* __restrict__ h3, float* __restrict__ g, int N) {
  __shared__ float sm[4][64];
  int w = threadIdx.x >> 6;
  int lane = threadIdx.x & 63;
  float acc = 0.f;
  for (int n = blockIdx.x * 4 + w; n < N; n += gridDim.x * 4)
    acc += h3[(size_t)n * 64 + lane];
  sm[w][lane] = acc;
  __syncthreads();
  if (w == 0) {
    float t = sm[0][lane] + sm[1][lane] + sm[2][lane] + sm[3][lane];
    atomicAdd(&g[lane], t);
  }
}

__global__ void final_k(const float* __restrict__ g, const float* __restrict__ Wc,
                        const float* __restrict__ bc, float* __restrict__ out, int N) {
  int lane = threadIdx.x;  // 64
  float gc = g[lane] / (float)N;
  for (int j = 0; j < 10; ++j) {
    float v = gc * Wc[lane * 10 + j];
    for (int off = 32; off; off >>= 1) v += __shfl_down(v, off);
    if (lane == 0) out[j] = v + bc[j];
  }
}

// ---------------- launch ----------------

extern "C" void kernel_launch(void* const* d_in, const int* in_sizes, int n_in,
                              void* d_out, int out_size, void* d_ws, size_t ws_size,
                              hipStream_t stream) {
  const float* x   = (const float*)d_in[0];
  const int*   ei  = (const int*)d_in[1];
  const float* W1  = (const float*)d_in[2];
  const float* as1 = (const float*)d_in[3];
  const float* ad1 = (const float*)d_in[4];
  const float* b1  = (const float*)d_in[5];
  const float* W2  = (const float*)d_in[6];
  const float* as2 = (const float*)d_in[7];
  const float* ad2 = (const float*)d_in[8];
  const float* b2  = (const float*)d_in[9];
  const float* W3  = (const float*)d_in[10];
  const float* as3 = (const float*)d_in[11];
  const float* ad3 = (const float*)d_in[12];
  const float* b3  = (const float*)d_in[13];
  const float* Wc  = (const float*)d_in[14];
  const float* bc  = (const float*)d_in[15];
  float* out = (float*)d_out;

  int N = in_sizes[0] / 128;
  int E = in_sizes[1] / 2;
  int E2 = E + N;

  char* w = (char*)d_ws;
  auto alloc = [&](size_t bytes) {
    char* p = w;
    w += (bytes + 255) & ~(size_t)255;
    return p;
  };
  ushort* xb   = (ushort*)alloc((size_t)N * 128 * 2);
  ushort* xwb  = (ushort*)alloc((size_t)N * 256 * 2);
  ushort* hb   = (ushort*)alloc((size_t)N * 256 * 2);
  float*  h3f  = (float*)alloc((size_t)N * 64 * 4);
  ushort* w1t  = (ushort*)alloc((size_t)256 * 128 * 2);
  ushort* w2t  = (ushort*)alloc((size_t)256 * 256 * 2);
  ushort* w3t  = (ushort*)alloc((size_t)64 * 256 * 2);
  float*  a_s  = (float*)alloc((size_t)N * 4 * 4);
  float*  a_d  = (float*)alloc((size_t)N * 4 * 4);
  int*   deg    = (int*)alloc((size_t)N * 4);
  int*   excl   = (int*)alloc((size_t)N * 4);
  int*   bsum   = (int*)alloc(64 * 4);
  int*   rowptr = (int*)alloc((size_t)(N + 1) * 4);
  int*   wptr   = (int*)alloc((size_t)N * 4);
  int*   csr    = (int*)alloc((size_t)E2 * 4);
  float* g      = (float*)alloc(64 * 4);

  hipMemsetAsync(deg, 0, (size_t)N * 4, stream);
  hipMemsetAsync(g, 0, 64 * 4, stream);

  // conversions
  f2b_k<<<(N * 128 / 4 + 255) / 256, 256, 0, stream>>>(x, xb, N * 128 / 4);
  wtrans_k<<<dim3(8, 16), 256, 0, stream>>>(W1, w1t, 128, 256);
  wtrans_k<<<dim3(16, 16), 256, 0, stream>>>(W2, w2t, 256, 256);
  wtrans_k<<<dim3(16, 4), 256, 0, stream>>>(W3, w3t, 256, 64);

  // CSR
  int gE2 = (E2 + 255) / 256;
  hist_k<<<gE2, 256, 0, stream>>>(ei, E, E2, deg);
  int nb = (N + 1023) / 1024;
  scan1_k<<<nb, 256, 0, stream>>>(deg, excl, bsum, N);
  scan2_k<<<1, 64, 0, stream>>>(bsum, nb);
  scan3_k<<<(N + 256) / 256, 256, 0, stream>>>(excl, bsum, rowptr, wptr, N, E2);
  scatter_k<<<gE2, 256, 0, stream>>>(ei, E, E2, wptr, csr);

  int mb = (N + 63) / 64;
  // layer 1: xb[N,128] @ W1 -> xwb[N,256]
  gemm_bf16<<<dim3(4, mb), 256, 0, stream>>>(xb, w1t, xwb, N, 256, 128);
  att_k<<<(N * 4 + 3) / 4, 256, 0, stream>>>(xwb, as1, ad1, a_s, a_d, N * 4, 4);
  agg4_k<4, 1><<<(N + 3) / 4, 256, 0, stream>>>(
      xwb, (const float4*)a_s, (const float4*)a_d, rowptr, csr, b1, hb, N);
  // layer 2: hb[N,256] @ W2 -> xwb[N,256]
  gemm_bf16<<<dim3(4, mb), 256, 0, stream>>>(hb, w2t, xwb, N, 256, 256);
  att_k<<<(N * 4 + 3) / 4, 256, 0, stream>>>(xwb, as2, ad2, a_s, a_d, N * 4, 4);
  agg4_k<4, 1><<<(N + 3) / 4, 256, 0, stream>>>(
      xwb, (const float4*)a_s, (const float4*)a_d, rowptr, csr, b2, hb, N);
  // layer 3: hb[N,256] @ W3 -> xwb[N,64] (single head)
  gemm_bf16<<<dim3(1, mb), 256, 0, stream>>>(hb, w3t, xwb, N, 64, 256);
  att_k<<<(N + 3) / 4, 256, 0, stream>>>(xwb, as3, ad3, a_s, a_d, N, 1);
  agg1_k<4><<<(N + 3) / 4, 256, 0, stream>>>(xwb, a_s, a_d, rowptr, csr, b3, h3f, N);

  reduce_mean_k<<<256, 256, 0, stream>>>(h3f, g, N);
  final_k<<<1, 64, 0, stream>>>(g, Wc, bc, out, N);
}

// Round 6
// 501.274 us; speedup vs baseline: 1.5350x; 1.0556x over previous
//
#include <hip/hip_runtime.h>

#define NEG_SLOPE 0.2f

typedef __attribute__((ext_vector_type(8))) short bf16x8;
typedef __attribute__((ext_vector_type(4))) float f32x4;

__device__ __forceinline__ float bf2f(ushort u) {
  return __uint_as_float(((unsigned int)u) << 16);
}
__device__ __forceinline__ ushort f2bf(float f) {  // round-to-nearest-even
  unsigned int u = __float_as_uint(f);
  u += 0x7fff + ((u >> 16) & 1);
  return (ushort)(u >> 16);
}
__device__ __forceinline__ float lrelu(float e) { return e > 0.f ? e : NEG_SLOPE * e; }

__device__ __forceinline__ float wave_max64(float v) {
  for (int off = 32; off; off >>= 1) v = fmaxf(v, __shfl_xor(v, off));
  return v;
}
__device__ __forceinline__ float wave_sum64(float v) {
  for (int off = 32; off; off >>= 1) v += __shfl_xor(v, off);
  return v;
}

// ---------------- CSR build ----------------

__global__ void hist_k(const int* __restrict__ ei, int E, int E2, int* __restrict__ deg) {
  int i = blockIdx.x * 256 + threadIdx.x;
  if (i >= E2) return;
  int d = (i < E) ? ei[E + i] : (i - E);
  atomicAdd(&deg[d], 1);
}

__global__ void scan1_k(const int* __restrict__ deg, int* __restrict__ excl,
                        int* __restrict__ bsum, int N) {
  __shared__ int sm[256];
  int t = threadIdx.x;
  int base = blockIdx.x * 1024 + t * 4;
  int v0 = (base + 0 < N) ? deg[base + 0] : 0;
  int v1 = (base + 1 < N) ? deg[base + 1] : 0;
  int v2 = (base + 2 < N) ? deg[base + 2] : 0;
  int v3 = (base + 3 < N) ? deg[base + 3] : 0;
  int tsum = v0 + v1 + v2 + v3;
  sm[t] = tsum;
  __syncthreads();
  for (int off = 1; off < 256; off <<= 1) {
    int x = (t >= off) ? sm[t - off] : 0;
    __syncthreads();
    sm[t] += x;
    __syncthreads();
  }
  int run = sm[t] - tsum;
  if (base + 0 < N) excl[base + 0] = run; run += v0;
  if (base + 1 < N) excl[base + 1] = run; run += v1;
  if (base + 2 < N) excl[base + 2] = run; run += v2;
  if (base + 3 < N) excl[base + 3] = run;
  if (t == 255) bsum[blockIdx.x] = sm[255];
}

__global__ void scan2_k(int* __restrict__ bsum, int nb) {
  int t = threadIdx.x;
  int orig = (t < nb) ? bsum[t] : 0;
  int v = orig;
  for (int off = 1; off < 64; off <<= 1) {
    int x = __shfl_up(v, off);
    if (t >= off) v += x;
  }
  if (t < nb) bsum[t] = v - orig;
}

__global__ void scan3_k(const int* __restrict__ excl, const int* __restrict__ bsum,
                        int* __restrict__ rowptr, int* __restrict__ wptr, int N, int E2) {
  int i = blockIdx.x * 256 + threadIdx.x;
  if (i < N) {
    int r = excl[i] + bsum[i >> 10];
    rowptr[i] = r;
    wptr[i] = r;
  }
  if (i == N) rowptr[N] = E2;
}

__global__ void scatter_k(const int* __restrict__ ei, int E, int E2,
                          int* __restrict__ wptr, int* __restrict__ csr_src) {
  int i = blockIdx.x * 256 + threadIdx.x;
  if (i >= E2) return;
  int s, d;
  if (i < E) { s = ei[i]; d = ei[E + i]; }
  else       { s = d = i - E; }
  int pos = atomicAdd(&wptr[d], 1);
  csr_src[pos] = s;
}

// ---------------- conversions ----------------

__global__ void f2b_k(const float* __restrict__ in, ushort* __restrict__ out, int n4) {
  int i = blockIdx.x * 256 + threadIdx.x;
  if (i >= n4) return;
  float4 v = ((const float4*)in)[i];
  ushort4 o;
  o.x = f2bf(v.x); o.y = f2bf(v.y); o.z = f2bf(v.z); o.w = f2bf(v.w);
  ((ushort4*)out)[i] = o;
}

// W[K][Nc] f32 -> Wt[Nc][K] bf16
__global__ void wtrans_k(const float* __restrict__ W, ushort* __restrict__ Wt, int K, int Nc) {
  int k = blockIdx.x * 16 + (threadIdx.x & 15);
  int n = blockIdx.y * 16 + (threadIdx.x >> 4);
  if (k < K && n < Nc) Wt[(size_t)n * K + k] = f2bf(W[(size_t)k * Nc + n]);
}

// ------- bf16 MFMA GEMM + fused attention coefficients -------
// C[M,N]=A[M,K]@B[K,N] (Bt[N][K] input). Each BN=64 tile is one head h=bn/64:
// epilogue computes a_s[row*H+h] = sum_c xw[row][h*64+c]*att_s[h][c] (and a_d).

__global__ __launch_bounds__(256) void gemm_att(const ushort* __restrict__ A,
                                                const ushort* __restrict__ Bt,
                                                ushort* __restrict__ C,
                                                const float* __restrict__ att_s,
                                                const float* __restrict__ att_d,
                                                float* __restrict__ a_s,
                                                float* __restrict__ a_d,
                                                int M, int N, int K, int H) {
  __shared__ ushort As[64][40];
  __shared__ ushort Bs[64][40];
  int tid = threadIdx.x;
  int w = tid >> 6, l = tid & 63;
  int bm = blockIdx.y * 64, bn = blockIdx.x * 64;
  int srow = tid >> 2, sseg = (tid & 3) * 8;
  bool aok = (bm + srow) < M;
  const ushort* Ap = A + (size_t)(bm + srow) * K + sseg;
  const ushort* Bp = Bt + (size_t)(bn + srow) * K + sseg;
  f32x4 acc[4];
#pragma unroll
  for (int nb = 0; nb < 4; ++nb) acc[nb] = (f32x4){0.f, 0.f, 0.f, 0.f};
  int fr = l & 15, fk = (l >> 4) * 8;
  for (int k0 = 0; k0 < K; k0 += 32) {
    bf16x8 av = {0, 0, 0, 0, 0, 0, 0, 0};
    if (aok) av = *(const bf16x8*)(Ap + k0);
    bf16x8 bv = *(const bf16x8*)(Bp + k0);
    *(bf16x8*)&As[srow][sseg] = av;
    *(bf16x8*)&Bs[srow][sseg] = bv;
    __syncthreads();
    bf16x8 af = *(bf16x8*)&As[16 * w + fr][fk];
#pragma unroll
    for (int nb = 0; nb < 4; ++nb) {
      bf16x8 bfv = *(bf16x8*)&Bs[nb * 16 + fr][fk];
      acc[nb] = __builtin_amdgcn_mfma_f32_16x16x32_bf16(af, bfv, acc[nb], 0, 0, 0);
    }
    __syncthreads();
  }
  int fg = l >> 4;
  // fused attention-coefficient epilogue
  int h = bn >> 6;
  float asc[4], adc[4];
#pragma unroll
  for (int nb = 0; nb < 4; ++nb) {
    asc[nb] = att_s[h * 64 + nb * 16 + fr];
    adc[nb] = att_d[h * 64 + nb * 16 + fr];
  }
#pragma unroll
  for (int r = 0; r < 4; ++r) {
    float vs = 0.f, vd = 0.f;
#pragma unroll
    for (int nb = 0; nb < 4; ++nb) {
      vs = fmaf(acc[nb][r], asc[nb], vs);
      vd = fmaf(acc[nb][r], adc[nb], vd);
    }
#pragma unroll
    for (int off = 1; off < 16; off <<= 1) {
      vs += __shfl_xor(vs, off);
      vd += __shfl_xor(vd, off);
    }
    int row = bm + 16 * w + fg * 4 + r;
    if (fr == 0 && row < M) {
      a_s[(size_t)row * H + h] = vs;
      a_d[(size_t)row * H + h] = vd;
    }
  }
#pragma unroll
  for (int nb = 0; nb < 4; ++nb)
#pragma unroll
    for (int r = 0; r < 4; ++r) {
      int row = bm + 16 * w + fg * 4 + r;
      if (row < M) C[(size_t)row * N + bn + nb * 16 + fr] = f2bf(acc[nb][r]);
    }
}

// ---------------- edge softmax weights (unnormalized) ----------------
// alpha[e] = exp(e - m[dst]) (per head); invs[n] = 1/sum. Wave per node.

template <int WPB>
__global__ __launch_bounds__(64 * WPB) void alpha4_k(
    const float4* __restrict__ a_s4, const float4* __restrict__ a_d4,
    const int* __restrict__ rowptr, const int* __restrict__ csr_src,
    float4* __restrict__ alpha, float4* __restrict__ invs, int N) {
  int w = threadIdx.x >> 6, l = threadIdx.x & 63;
  int n = blockIdx.x * WPB + w;
  if (n >= N) return;
  int beg = rowptr[n], end = rowptr[n + 1];
  float4 ad = a_d4[n];
  float m0 = -1e30f, m1 = -1e30f, m2 = -1e30f, m3 = -1e30f;
  for (int c0 = beg; c0 < end; c0 += 64) {
    int cnt = min(64, end - c0);
    float e0 = -1e30f, e1 = -1e30f, e2 = -1e30f, e3 = -1e30f;
    if (l < cnt) {
      float4 as = a_s4[csr_src[c0 + l]];
      e0 = lrelu(as.x + ad.x); e1 = lrelu(as.y + ad.y);
      e2 = lrelu(as.z + ad.z); e3 = lrelu(as.w + ad.w);
    }
    m0 = fmaxf(m0, wave_max64(e0));
    m1 = fmaxf(m1, wave_max64(e1));
    m2 = fmaxf(m2, wave_max64(e2));
    m3 = fmaxf(m3, wave_max64(e3));
  }
  float s0 = 0.f, s1 = 0.f, s2 = 0.f, s3 = 0.f;
  for (int c0 = beg; c0 < end; c0 += 64) {
    int cnt = min(64, end - c0);
    float p0 = 0.f, p1 = 0.f, p2 = 0.f, p3 = 0.f;
    if (l < cnt) {
      float4 as = a_s4[csr_src[c0 + l]];
      p0 = __expf(lrelu(as.x + ad.x) - m0);
      p1 = __expf(lrelu(as.y + ad.y) - m1);
      p2 = __expf(lrelu(as.z + ad.z) - m2);
      p3 = __expf(lrelu(as.w + ad.w) - m3);
      alpha[c0 + l] = make_float4(p0, p1, p2, p3);
    }
    s0 += wave_sum64(p0); s1 += wave_sum64(p1);
    s2 += wave_sum64(p2); s3 += wave_sum64(p3);
  }
  if (l == 0) invs[n] = make_float4(1.f / s0, 1.f / s1, 1.f / s2, 1.f / s3);
}

template <int WPB>
__global__ __launch_bounds__(64 * WPB) void alpha1_k(
    const float* __restrict__ a_s, const float* __restrict__ a_d,
    const int* __restrict__ rowptr, const int* __restrict__ csr_src,
    float* __restrict__ alpha, float* __restrict__ invs, int N) {
  int w = threadIdx.x >> 6, l = threadIdx.x & 63;
  int n = blockIdx.x * WPB + w;
  if (n >= N) return;
  int beg = rowptr[n], end = rowptr[n + 1];
  float ad = a_d[n];
  float m = -1e30f;
  for (int c0 = beg; c0 < end; c0 += 64) {
    int cnt = min(64, end - c0);
    float e = -1e30f;
    if (l < cnt) e = lrelu(a_s[csr_src[c0 + l]] + ad);
    m = fmaxf(m, wave_max64(e));
  }
  float s = 0.f;
  for (int c0 = beg; c0 < end; c0 += 64) {
    int cnt = min(64, end - c0);
    float p = 0.f;
    if (l < cnt) {
      p = __expf(lrelu(a_s[csr_src[c0 + l]] + ad) - m);
      alpha[c0 + l] = p;
    }
    s += wave_sum64(p);
  }
  if (l == 0) invs[n] = 1.f / s;
}

// ---------------- aggregation, H=4: pure weighted gather ----------------
// wave = node; lane = (head l>>4, 4 channels). sidx broadcast via readlane (SGPR),
// alpha via conflict-free LDS broadcast; unroll x2, dual accumulators.

template <int WPB, int ACT>
__global__ __launch_bounds__(64 * WPB) void agg4_k(
    const ushort* __restrict__ xw, const float4* __restrict__ alpha,
    const float4* __restrict__ invs, const int* __restrict__ rowptr,
    const int* __restrict__ csr_src, const float* __restrict__ bias,
    ushort* __restrict__ hout, int N) {
  __shared__ float pbuf[WPB][4][66];
  int w = threadIdx.x >> 6, l = threadIdx.x & 63;
  int n = blockIdx.x * WPB + w;
  if (n >= N) return;
  int h = l >> 4;
  int beg = rowptr[n], end = rowptr[n + 1];
  f32x4 accA = {0.f, 0.f, 0.f, 0.f}, accB = {0.f, 0.f, 0.f, 0.f};
  const ushort4* xw4 = (const ushort4*)xw;
  for (int c0 = beg; c0 < end; c0 += 64) {
    int cnt = min(64, end - c0);
    int sidx = 0;
    float4 p = make_float4(0.f, 0.f, 0.f, 0.f);
    if (l < cnt) {
      sidx = csr_src[c0 + l];
      p = alpha[c0 + l];
    }
    pbuf[w][0][l] = p.x; pbuf[w][1][l] = p.y;
    pbuf[w][2][l] = p.z; pbuf[w][3][l] = p.w;
    // single-wave LDS producer/consumer: in-order, no barrier
    int j = 0;
    for (; j + 2 <= cnt; j += 2) {
      int sj0 = __builtin_amdgcn_readlane(sidx, j);
      int sj1 = __builtin_amdgcn_readlane(sidx, j + 1);
      float pj0 = pbuf[w][h][j];
      float pj1 = pbuf[w][h][j + 1];
      ushort4 v0 = xw4[(size_t)sj0 * 64 + l];
      ushort4 v1 = xw4[(size_t)sj1 * 64 + l];
      accA[0] = fmaf(pj0, bf2f(v0.x), accA[0]);
      accA[1] = fmaf(pj0, bf2f(v0.y), accA[1]);
      accA[2] = fmaf(pj0, bf2f(v0.z), accA[2]);
      accA[3] = fmaf(pj0, bf2f(v0.w), accA[3]);
      accB[0] = fmaf(pj1, bf2f(v1.x), accB[0]);
      accB[1] = fmaf(pj1, bf2f(v1.y), accB[1]);
      accB[2] = fmaf(pj1, bf2f(v1.z), accB[2]);
      accB[3] = fmaf(pj1, bf2f(v1.w), accB[3]);
    }
    if (j < cnt) {
      int sj = __builtin_amdgcn_readlane(sidx, j);
      float pj = pbuf[w][h][j];
      ushort4 v = xw4[(size_t)sj * 64 + l];
      accA[0] = fmaf(pj, bf2f(v.x), accA[0]);
      accA[1] = fmaf(pj, bf2f(v.y), accA[1]);
      accA[2] = fmaf(pj, bf2f(v.z), accA[2]);
      accA[3] = fmaf(pj, bf2f(v.w), accA[3]);
    }
  }
  float4 iv = invs[n];
  float inv = h == 0 ? iv.x : h == 1 ? iv.y : h == 2 ? iv.z : iv.w;
  float4 bv = ((const float4*)bias)[l];
  float o0 = (accA[0] + accB[0]) * inv + bv.x;
  float o1 = (accA[1] + accB[1]) * inv + bv.y;
  float o2 = (accA[2] + accB[2]) * inv + bv.z;
  float o3 = (accA[3] + accB[3]) * inv + bv.w;
  if (ACT) {
    o0 = o0 > 0.f ? o0 : __expf(o0) - 1.f;
    o1 = o1 > 0.f ? o1 : __expf(o1) - 1.f;
    o2 = o2 > 0.f ? o2 : __expf(o2) - 1.f;
    o3 = o3 > 0.f ? o3 : __expf(o3) - 1.f;
  }
  ushort4 ov;
  ov.x = f2bf(o0); ov.y = f2bf(o1); ov.z = f2bf(o2); ov.w = f2bf(o3);
  ((ushort4*)(hout + (size_t)n * 256))[l] = ov;
}

// ---------------- aggregation, H=1 (layer 3): 4 edges/iter ----------------

template <int WPB>
__global__ __launch_bounds__(64 * WPB) void agg1_k(
    const ushort* __restrict__ xw, const float* __restrict__ alpha,
    const float* __restrict__ invs, const int* __restrict__ rowptr,
    const int* __restrict__ csr_src, const float* __restrict__ bias,
    float* __restrict__ hout, int N) {
  __shared__ float pbuf[WPB][64];
  __shared__ int sbuf[WPB][64];
  int w = threadIdx.x >> 6, l = threadIdx.x & 63;
  int n = blockIdx.x * WPB + w;
  if (n >= N) return;
  int g = l >> 4, q = l & 15;
  int beg = rowptr[n], end = rowptr[n + 1];
  f32x4 acc = {0.f, 0.f, 0.f, 0.f};
  const ushort4* xw4 = (const ushort4*)xw;
  for (int c0 = beg; c0 < end; c0 += 64) {
    int cnt = min(64, end - c0);
    int sidx = 0;
    float p = 0.f;
    if (l < cnt) {
      sidx = csr_src[c0 + l];
      p = alpha[c0 + l];
    }
    pbuf[w][l] = p;
    sbuf[w][l] = sidx;
    for (int j = 0; j < cnt; j += 4) {
      int jj = j + g;
      bool ok = jj < cnt;
      int idx = ok ? jj : 0;
      float pj = ok ? pbuf[w][idx] : 0.f;
      int sj = sbuf[w][idx];
      ushort4 v = xw4[(size_t)sj * 16 + q];
      acc[0] = fmaf(pj, bf2f(v.x), acc[0]);
      acc[1] = fmaf(pj, bf2f(v.y), acc[1]);
      acc[2] = fmaf(pj, bf2f(v.z), acc[2]);
      acc[3] = fmaf(pj, bf2f(v.w), acc[3]);
    }
  }
#pragma unroll
  for (int i = 0; i < 4; ++i) {
    acc[i] += __shfl_xor(acc[i], 16);
    acc[i] += __shfl_xor(acc[i], 32);
  }
  float inv = invs[n];
  float4 bv = ((const float4*)bias)[q];
  float4 o;
  o.x = acc[0] * inv + bv.x;
  o.y = acc[1] * inv + bv.y;
  o.z = acc[2] * inv + bv.z;
  o.w = acc[3] * inv + bv.w;
  if (g == 0) ((float4*)(hout + (size_t)n * 64))[q] = o;
}

// ---------------- final mean over nodes + classifier ----------------

__global__ void reduce_mean_k(const float* __restrict__ h3, float* __restrict__ g, int N) {
  __shared__ float sm[4][64];
  int w = threadIdx.x >> 6;
  int lane = threadIdx.x & 63;
  float acc = 0.f;
  for (int n = blockIdx.x * 4 + w; n < N; n += gridDim.x * 4)
    acc += h3[(size_t)n * 64 + lane];
  sm[w][lane] = acc;
  __syncthreads();
  if (w == 0) {
    float t = sm[0][lane] + sm[1][lane] + sm[2][lane] + sm[3][lane];
    atomicAdd(&g[lane], t);
  }
}

__global__ void final_k(const float* __restrict__ g, const float* __restrict__ Wc,
                        const float* __restrict__ bc, float* __restrict__ out, int N) {
  int lane = threadIdx.x;  // 64
  float gc = g[lane] / (float)N;
  for (int j = 0; j < 10; ++j) {
    float v = gc * Wc[lane * 10 + j];
    for (int off = 32; off; off >>= 1) v += __shfl_down(v, off);
    if (lane == 0) out[j] = v + bc[j];
  }
}

// ---------------- launch ----------------

extern "C" void kernel_launch(void* const* d_in, const int* in_sizes, int n_in,
                              void* d_out, int out_size, void* d_ws, size_t ws_size,
                              hipStream_t stream) {
  const float* x   = (const float*)d_in[0];
  const int*   ei  = (const int*)d_in[1];
  const float* W1  = (const float*)d_in[2];
  const float* as1 = (const float*)d_in[3];
  const float* ad1 = (const float*)d_in[4];
  const float* b1  = (const float*)d_in[5];
  const float* W2  = (const float*)d_in[6];
  const float* as2 = (const float*)d_in[7];
  const float* ad2 = (const float*)d_in[8];
  const float* b2  = (const float*)d_in[9];
  const float* W3  = (const float*)d_in[10];
  const float* as3 = (const float*)d_in[11];
  const float* ad3 = (const float*)d_in[12];
  const float* b3  = (const float*)d_in[13];
  const float* Wc  = (const float*)d_in[14];
  const float* bc  = (const float*)d_in[15];
  float* out = (float*)d_out;

  int N = in_sizes[0] / 128;
  int E = in_sizes[1] / 2;
  int E2 = E + N;

  char* w = (char*)d_ws;
  auto alloc = [&](size_t bytes) {
    char* p = w;
    w += (bytes + 255) & ~(size_t)255;
    return p;
  };
  ushort* xb   = (ushort*)alloc((size_t)N * 128 * 2);  // reused as h3f (layer 3, f32[N][64])
  float*  h3f  = (float*)xb;
  ushort* xwb  = (ushort*)alloc((size_t)N * 256 * 2);
  ushort* hb   = (ushort*)alloc((size_t)N * 256 * 2);
  float*  alph = (float*)alloc((size_t)E2 * 4 * 4);
  float*  invs = (float*)alloc((size_t)N * 4 * 4);
  ushort* w1t  = (ushort*)alloc((size_t)256 * 128 * 2);
  ushort* w2t  = (ushort*)alloc((size_t)256 * 256 * 2);
  ushort* w3t  = (ushort*)alloc((size_t)64 * 256 * 2);
  float*  a_s  = (float*)alloc((size_t)N * 4 * 4);
  float*  a_d  = (float*)alloc((size_t)N * 4 * 4);
  int*   deg    = (int*)alloc((size_t)N * 4);
  int*   excl   = (int*)alloc((size_t)N * 4);
  int*   bsum   = (int*)alloc(64 * 4);
  int*   rowptr = (int*)alloc((size_t)(N + 1) * 4);
  int*   wptr   = (int*)alloc((size_t)N * 4);
  int*   csr    = (int*)alloc((size_t)E2 * 4);
  float* g      = (float*)alloc(64 * 4);

  hipMemsetAsync(deg, 0, (size_t)N * 4, stream);
  hipMemsetAsync(g, 0, 64 * 4, stream);

  // conversions
  f2b_k<<<(N * 128 / 4 + 255) / 256, 256, 0, stream>>>(x, xb, N * 128 / 4);
  wtrans_k<<<dim3(8, 16), 256, 0, stream>>>(W1, w1t, 128, 256);
  wtrans_k<<<dim3(16, 16), 256, 0, stream>>>(W2, w2t, 256, 256);
  wtrans_k<<<dim3(16, 4), 256, 0, stream>>>(W3, w3t, 256, 64);

  // CSR
  int gE2 = (E2 + 255) / 256;
  hist_k<<<gE2, 256, 0, stream>>>(ei, E, E2, deg);
  int nb = (N + 1023) / 1024;
  scan1_k<<<nb, 256, 0, stream>>>(deg, excl, bsum, N);
  scan2_k<<<1, 64, 0, stream>>>(bsum, nb);
  scan3_k<<<(N + 256) / 256, 256, 0, stream>>>(excl, bsum, rowptr, wptr, N, E2);
  scatter_k<<<gE2, 256, 0, stream>>>(ei, E, E2, wptr, csr);

  int mb = (N + 63) / 64;
  int nwb = (N + 3) / 4;
  // layer 1
  gemm_att<<<dim3(4, mb), 256, 0, stream>>>(xb, w1t, xwb, as1, ad1, a_s, a_d, N, 256, 128, 4);
  alpha4_k<4><<<nwb, 256, 0, stream>>>((const float4*)a_s, (const float4*)a_d, rowptr, csr,
                                       (float4*)alph, (float4*)invs, N);
  agg4_k<4, 1><<<nwb, 256, 0, stream>>>(xwb, (const float4*)alph, (const float4*)invs,
                                        rowptr, csr, b1, hb, N);
  // layer 2
  gemm_att<<<dim3(4, mb), 256, 0, stream>>>(hb, w2t, xwb, as2, ad2, a_s, a_d, N, 256, 256, 4);
  alpha4_k<4><<<nwb, 256, 0, stream>>>((const float4*)a_s, (const float4*)a_d, rowptr, csr,
                                       (float4*)alph, (float4*)invs, N);
  agg4_k<4, 1><<<nwb, 256, 0, stream>>>(xwb, (const float4*)alph, (const float4*)invs,
                                        rowptr, csr, b2, hb, N);
  // layer 3 (single head)
  gemm_att<<<dim3(1, mb), 256, 0, stream>>>(hb, w3t, xwb, as3, ad3, a_s, a_d, N, 64, 256, 1);
  alpha1_k<4><<<nwb, 256, 0, stream>>>(a_s, a_d, rowptr, csr, alph, invs, N);
  agg1_k<4><<<nwb, 256, 0, stream>>>(xwb, alph, invs, rowptr, csr, b3, h3f, N);

  reduce_mean_k<<<256, 256, 0, stream>>>(h3f, g, N);
  final_k<<<1, 64, 0, stream>>>(g, Wc, bc, out, N);
}